// Round 13
// baseline (104.668 us; speedup 1.0000x reference)
//
#include <hip/hip_runtime.h>
#include <hip/hip_bf16.h>

#define SEQ 2048
#define DIMH 64
#define KB 64
#define NT (SEQ / KB)

typedef __attribute__((ext_vector_type(8))) short bf16x8;
typedef __attribute__((ext_vector_type(4))) float f32x4;

extern "C" __device__ float __ocml_native_exp2_f32(float);
#define EXP2(x) __ocml_native_exp2_f32(x)

__device__ inline unsigned short f2bf(float f) {
    union { __bf16 h; unsigned short u; } c;
    c.h = (__bf16)f;
    return c.u;
}
__device__ inline unsigned pack2(float a, float b) {
    return (unsigned)f2bf(a) | ((unsigned)f2bf(b) << 16);
}

// Two-level XOR swizzle within a [rows][64]-ushort tile.
__device__ inline int swz(int row, int col) {
    int g = (((row & 7) ^ ((row >> 3) & 7)) << 3);
    return row * 64 + (col ^ g);
}

// VALU cross-lane swaps (gfx950). After perm32 then perm16 on (a,b):
//   a = { A@lg0, A@lg2, B@lg0, B@lg2 },  b = { A@lg1, A@lg3, B@lg1, B@lg3 }
__device__ inline void perm32swap(unsigned &a, unsigned &b) {
    asm("v_permlane32_swap_b32 %0, %1" : "+v"(a), "+v"(b));
}
__device__ inline void perm16swap(unsigned &a, unsigned &b) {
    asm("v_permlane16_swap_b32 %0, %1" : "+v"(a), "+v"(b));
}

__global__ __launch_bounds__(256, 4) void fattn(
    const float* __restrict__ Q, const float* __restrict__ K,
    const float* __restrict__ V, float* __restrict__ O)
{
    __shared__ __align__(16) unsigned short Ksh[2][KB * DIMH];  // [kv][dim], swizzled, dbuf
    __shared__ __align__(16) unsigned short Vt[2][KB * DIMH];   // [dim][kv], swizzled, dbuf

    const int tid  = threadIdx.x;
    const int lane = tid & 63;
    const int wv   = tid >> 6;

    // XCD swizzle: 1024 = 8 XCDs x 128; head's K/V pinned to one XCD's L2
    // (r11: FETCH 278->49 MB; staging loads become L2 hits).
    const int bid = blockIdx.x;
    const int swb = (bid & 7) * 128 + (bid >> 3);
    const int bh  = swb >> 4;
    const int qt  = swb & 15;

    const int l15 = lane & 15;
    const int lg  = lane >> 4;          // 0..3

    const float* qh = Q + (size_t)bh * SEQ * DIMH;
    const float* kh = K + (size_t)bh * SEQ * DIMH;
    const float* vh = V + (size_t)bh * SEQ * DIMH;
    float*       oh = O + (size_t)bh * SEQ * DIMH;

    const int q0 = qt * 128 + wv * 32;

    int koff[4][2];
    #pragma unroll
    for (int n = 0; n < 4; ++n)
        #pragma unroll
        for (int ks = 0; ks < 2; ++ks)
            koff[n][ks] = swz(n * 16 + l15, ks * 32 + lg * 8);

    const int c4 = (tid & 15) * 4;
    const int rK = tid >> 4;
    int kstoff[4], vstoff[4];
    #pragma unroll
    for (int rr = 0; rr < 4; ++rr) kstoff[rr] = swz(rr * 16 + rK, c4);
    #pragma unroll
    for (int j = 0; j < 4; ++j) vstoff[j] = swz(c4 + j, rK * 4);

    const float QS = 0.180336880111120f;  // log2(e) / 8
    bf16x8 qf[2][2];
    #pragma unroll
    for (int h = 0; h < 2; ++h)
        #pragma unroll
        for (int ks = 0; ks < 2; ++ks) {
            const float* src = qh + (size_t)(q0 + h * 16 + l15) * DIMH + ks * 32 + lg * 8;
            f32x4 a = *reinterpret_cast<const f32x4*>(src);
            f32x4 b = *reinterpret_cast<const f32x4*>(src + 4);
            bf16x8 vq;
            #pragma unroll
            for (int j = 0; j < 4; ++j) {
                vq[j]     = (short)f2bf(a[j] * QS);
                vq[j + 4] = (short)f2bf(b[j] * QS);
            }
            qf[h][ks] = vq;
        }

    bf16x8 ones;
    #pragma unroll
    for (int j = 0; j < 8; ++j) ones[j] = (short)0x3F80;

    f32x4 oacc[2][4];
    #pragma unroll
    for (int h = 0; h < 2; ++h)
        #pragma unroll
        for (int d = 0; d < 4; ++d) oacc[h][d] = (f32x4){0.f, 0.f, 0.f, 0.f};
    f32x4 lacc[2] = {{0.f,0.f,0.f,0.f}, {0.f,0.f,0.f,0.f}};

    // ---- prologue: stage tile 0 into buf 0 ----
    {
        #pragma unroll
        for (int rr = 0; rr < 4; ++rr) {
            const f32x4 k4 = *reinterpret_cast<const f32x4*>(
                kh + (size_t)(rr * 16 + rK) * DIMH + c4);
            uint2 kk;
            kk.x = pack2(k4[0], k4[1]);
            kk.y = pack2(k4[2], k4[3]);
            *reinterpret_cast<uint2*>(&Ksh[0][kstoff[rr]]) = kk;
        }
        f32x4 v4[4];
        #pragma unroll
        for (int i = 0; i < 4; ++i)
            v4[i] = *reinterpret_cast<const f32x4*>(
                vh + (size_t)(rK * 4 + i) * DIMH + c4);
        #pragma unroll
        for (int j = 0; j < 4; ++j) {
            uint2 w;
            w.x = pack2(v4[0][j], v4[1][j]);
            w.y = pack2(v4[2][j], v4[3][j]);
            *reinterpret_cast<uint2*>(&Vt[0][vstoff[j]]) = w;
        }
    }
    __syncthreads();

    for (int kt = 0; kt < NT; ++kt) {
        const int cur = kt & 1;
        const int nxt = cur ^ 1;
        const unsigned short* Kb = Ksh[cur];
        const unsigned short* Vb = Vt[cur];
        const bool pf = (kt + 1 < NT);

        // ---- stage tile kt+1 into buf[nxt]: load -> cvt -> write, contiguous.
        // Writes to nxt are WAR-safe: nxt's readers finished before the
        // previous iteration's end barrier. Short register live range
        // (same as r11's staging) -> no spill under the 64-VGPR pin.
        if (pf) {
            const size_t tb = (size_t)(kt + 1) * KB;
            #pragma unroll
            for (int rr = 0; rr < 4; ++rr) {
                const f32x4 k4 = *reinterpret_cast<const f32x4*>(
                    kh + (tb + rr * 16 + rK) * DIMH + c4);
                uint2 kk;
                kk.x = pack2(k4[0], k4[1]);
                kk.y = pack2(k4[2], k4[3]);
                *reinterpret_cast<uint2*>(&Ksh[nxt][kstoff[rr]]) = kk;
            }
            f32x4 v4[4];
            #pragma unroll
            for (int i = 0; i < 4; ++i)
                v4[i] = *reinterpret_cast<const f32x4*>(
                    vh + (tb + rK * 4 + i) * DIMH + c4);
            #pragma unroll
            for (int j = 0; j < 4; ++j) {
                uint2 w;
                w.x = pack2(v4[0][j], v4[1][j]);
                w.y = pack2(v4[2][j], v4[3][j]);
                *reinterpret_cast<uint2*>(&Vt[nxt][vstoff[j]]) = w;
            }
        }

        __builtin_amdgcn_s_setprio(1);

        // ---- S^T = K (Q*QS)^T fused with exp2 ----
        unsigned u[2][8];
        #pragma unroll
        for (int n = 0; n < 4; ++n) {
            bf16x8 kf0 = *reinterpret_cast<const bf16x8*>(&Kb[koff[n][0]]);
            bf16x8 kf1 = *reinterpret_cast<const bf16x8*>(&Kb[koff[n][1]]);
            #pragma unroll
            for (int h = 0; h < 2; ++h) {
                f32x4 a = {0.f, 0.f, 0.f, 0.f};
                a = __builtin_amdgcn_mfma_f32_16x16x32_bf16(kf0, qf[h][0], a, 0, 0, 0);
                a = __builtin_amdgcn_mfma_f32_16x16x32_bf16(kf1, qf[h][1], a, 0, 0, 0);
                u[h][2 * n]     = pack2(EXP2(a[0]), EXP2(a[1]));
                u[h][2 * n + 1] = pack2(EXP2(a[2]), EXP2(a[3]));
            }
        }

        // ---- T12 exchange: D-layout -> A-frag, pure VALU ----
        bf16x8 pa[2][2];
        #pragma unroll
        for (int h = 0; h < 2; ++h)
            #pragma unroll
            for (int ks = 0; ks < 2; ++ks) {
                unsigned a0 = u[h][4 * ks + 0], b0 = u[h][4 * ks + 2];
                unsigned a1 = u[h][4 * ks + 1], b1 = u[h][4 * ks + 3];
                perm32swap(a0, b0); perm16swap(a0, b0);
                perm32swap(a1, b1); perm16swap(a1, b1);
                union { unsigned w[4]; bf16x8 v; } pu;
                pu.w[0] = a0; pu.w[1] = a1; pu.w[2] = b0; pu.w[3] = b1;
                pa[h][ks] = pu.v;
            }

        // ---- row sums via MFMA against ones ----
        #pragma unroll
        for (int h = 0; h < 2; ++h) {
            lacc[h] = __builtin_amdgcn_mfma_f32_16x16x32_bf16(pa[h][0], ones, lacc[h], 0, 0, 0);
            lacc[h] = __builtin_amdgcn_mfma_f32_16x16x32_bf16(pa[h][1], ones, lacc[h], 0, 0, 0);
        }

        // ---- O += P V ----
        #pragma unroll
        for (int d = 0; d < 4; ++d) {
            bf16x8 vb0 = *reinterpret_cast<const bf16x8*>(&Vb[koff[d][0]]);
            bf16x8 vb1 = *reinterpret_cast<const bf16x8*>(&Vb[koff[d][1]]);
            #pragma unroll
            for (int h = 0; h < 2; ++h) {
                oacc[h][d] = __builtin_amdgcn_mfma_f32_16x16x32_bf16(pa[h][0], vb0, oacc[h][d], 0, 0, 0);
                oacc[h][d] = __builtin_amdgcn_mfma_f32_16x16x32_bf16(pa[h][1], vb1, oacc[h][d], 0, 0, 0);
            }
        }

        __builtin_amdgcn_s_setprio(0);

        // ---- single end-of-iter barrier (drains this wave's LDS ops) ----
        if (pf) {
            asm volatile("s_waitcnt lgkmcnt(0)" ::: "memory");
            __builtin_amdgcn_s_barrier();
            asm volatile("" ::: "memory");
        }
    }

    // ---- epilogue: normalize by row sum, store fp32 ----
    #pragma unroll
    for (int h = 0; h < 2; ++h)
        #pragma unroll
        for (int r = 0; r < 4; ++r) {
            float inv = 1.0f / lacc[h][r];
            float* dst = oh + (size_t)(q0 + h * 16 + lg * 4 + r) * DIMH;
            #pragma unroll
            for (int d = 0; d < 4; ++d)
                dst[d * 16 + l15] = oacc[h][d][r] * inv;
        }
}

extern "C" void kernel_launch(void* const* d_in, const int* in_sizes, int n_in,
                              void* d_out, int out_size, void* d_ws, size_t ws_size,
                              hipStream_t stream) {
    const float* q = (const float*)d_in[0];
    const float* k = (const float*)d_in[1];
    const float* v = (const float*)d_in[2];
    float* out = (float*)d_out;
    dim3 grid(64 * (SEQ / 128));   // 64 heads x 16 q-tiles = 1024 blocks
    dim3 block(256);
    fattn<<<grid, block, 0, stream>>>(q, k, v, out);
}

// Round 14
// 91.825 us; speedup vs baseline: 1.1399x; 1.1399x over previous
//
#include <hip/hip_runtime.h>
#include <hip/hip_bf16.h>

#define SEQ 2048
#define DIMH 64
#define KB 64
#define NT (SEQ / KB)

typedef __attribute__((ext_vector_type(8))) short bf16x8;
typedef __attribute__((ext_vector_type(4))) float f32x4;

extern "C" __device__ float __ocml_native_exp2_f32(float);
#define EXP2(x) __ocml_native_exp2_f32(x)

__device__ inline unsigned short f2bf(float f) {
    union { __bf16 h; unsigned short u; } c;
    c.h = (__bf16)f;
    return c.u;
}
__device__ inline unsigned pack2(float a, float b) {
    return (unsigned)f2bf(a) | ((unsigned)f2bf(b) << 16);
}

// Two-level XOR swizzle within a [rows][64]-ushort tile.
__device__ inline int swz(int row, int col) {
    int g = (((row & 7) ^ ((row >> 3) & 7)) << 3);
    return row * 64 + (col ^ g);
}

// VALU cross-lane swaps (gfx950). After perm32 then perm16 on (a,b):
//   a = { A@lg0, A@lg2, B@lg0, B@lg2 },  b = { A@lg1, A@lg3, B@lg1, B@lg3 }
__device__ inline void perm32swap(unsigned &a, unsigned &b) {
    asm("v_permlane32_swap_b32 %0, %1" : "+v"(a), "+v"(b));
}
__device__ inline void perm16swap(unsigned &a, unsigned &b) {
    asm("v_permlane16_swap_b32 %0, %1" : "+v"(a), "+v"(b));
}

// 64 q-rows per wave: LDS fragment reads (16 b128/iter) serve 2x the MFMA
// work vs the 32-row version. grid=512 fills exactly 2 blocks/CU, so
// __launch_bounds__(256,2) (256-VGPR class) costs no occupancy.
__global__ __launch_bounds__(256, 2) void fattn(
    const float* __restrict__ Q, const float* __restrict__ K,
    const float* __restrict__ V, float* __restrict__ O)
{
    __shared__ __align__(16) unsigned short Ksh[2][KB * DIMH];  // [kv][dim], dbuf
    __shared__ __align__(16) unsigned short Vt[2][KB * DIMH];   // [dim][kv], dbuf

    const int tid  = threadIdx.x;
    const int lane = tid & 63;
    const int wv   = tid >> 6;

    // XCD swizzle: 512 = 8 XCDs x 64; heads 8x..8x+7 (8 blocks each) land
    // entirely on XCD x -> K/V stay hot in that XCD's L2 (r11: FETCH 5.7x down).
    const int bid = blockIdx.x;
    const int swb = (bid & 7) * 64 + (bid >> 3);
    const int bh  = swb >> 3;           // head (B*H = 64)
    const int qt  = swb & 7;            // q-tile of 256 rows

    const int l15 = lane & 15;
    const int lg  = lane >> 4;          // 0..3

    const float* qh = Q + (size_t)bh * SEQ * DIMH;
    const float* kh = K + (size_t)bh * SEQ * DIMH;
    const float* vh = V + (size_t)bh * SEQ * DIMH;
    float*       oh = O + (size_t)bh * SEQ * DIMH;

    const int q0 = qt * 256 + wv * 64;  // this wave's first q row (64 rows)

    int koff[4][2];
    #pragma unroll
    for (int n = 0; n < 4; ++n)
        #pragma unroll
        for (int ks = 0; ks < 2; ++ks)
            koff[n][ks] = swz(n * 16 + l15, ks * 32 + lg * 8);

    const int c4 = (tid & 15) * 4;
    const int rK = tid >> 4;
    int kstoff[4], vstoff[4];
    #pragma unroll
    for (int rr = 0; rr < 4; ++rr) kstoff[rr] = swz(rr * 16 + rK, c4);
    #pragma unroll
    for (int j = 0; j < 4; ++j) vstoff[j] = swz(c4 + j, rK * 4);

    const float QS = 0.180336880111120f;  // log2(e) / 8
    bf16x8 qf[4][2];                      // four 16-row groups
    #pragma unroll
    for (int h = 0; h < 4; ++h)
        #pragma unroll
        for (int ks = 0; ks < 2; ++ks) {
            const float* src = qh + (size_t)(q0 + h * 16 + l15) * DIMH + ks * 32 + lg * 8;
            f32x4 a = *reinterpret_cast<const f32x4*>(src);
            f32x4 b = *reinterpret_cast<const f32x4*>(src + 4);
            bf16x8 vq;
            #pragma unroll
            for (int j = 0; j < 4; ++j) {
                vq[j]     = (short)f2bf(a[j] * QS);
                vq[j + 4] = (short)f2bf(b[j] * QS);
            }
            qf[h][ks] = vq;
        }

    bf16x8 ones;
    #pragma unroll
    for (int j = 0; j < 8; ++j) ones[j] = (short)0x3F80;

    f32x4 oacc[4][4];
    #pragma unroll
    for (int h = 0; h < 4; ++h)
        #pragma unroll
        for (int d = 0; d < 4; ++d) oacc[h][d] = (f32x4){0.f, 0.f, 0.f, 0.f};
    f32x4 lacc[4] = {{0.f,0.f,0.f,0.f}, {0.f,0.f,0.f,0.f},
                     {0.f,0.f,0.f,0.f}, {0.f,0.f,0.f,0.f}};

    // ---- prologue: stage tile 0 into buf 0 ----
    {
        #pragma unroll
        for (int rr = 0; rr < 4; ++rr) {
            const f32x4 k4 = *reinterpret_cast<const f32x4*>(
                kh + (size_t)(rr * 16 + rK) * DIMH + c4);
            uint2 kk;
            kk.x = pack2(k4[0], k4[1]);
            kk.y = pack2(k4[2], k4[3]);
            *reinterpret_cast<uint2*>(&Ksh[0][kstoff[rr]]) = kk;
        }
        f32x4 v4[4];
        #pragma unroll
        for (int i = 0; i < 4; ++i)
            v4[i] = *reinterpret_cast<const f32x4*>(
                vh + (size_t)(rK * 4 + i) * DIMH + c4);
        #pragma unroll
        for (int j = 0; j < 4; ++j) {
            uint2 w;
            w.x = pack2(v4[0][j], v4[1][j]);
            w.y = pack2(v4[2][j], v4[3][j]);
            *reinterpret_cast<uint2*>(&Vt[0][vstoff[j]]) = w;
        }
    }
    __syncthreads();

    for (int kt = 0; kt < NT; ++kt) {
        const int cur = kt & 1;
        const int nxt = cur ^ 1;
        const unsigned short* Kb = Ksh[cur];
        const unsigned short* Vb = Vt[cur];
        const bool pf = (kt + 1 < NT);

        // ---- stage tile kt+1 into buf[nxt] (load -> cvt -> write, WAR-safe) ----
        if (pf) {
            const size_t tb = (size_t)(kt + 1) * KB;
            #pragma unroll
            for (int rr = 0; rr < 4; ++rr) {
                const f32x4 k4 = *reinterpret_cast<const f32x4*>(
                    kh + (tb + rr * 16 + rK) * DIMH + c4);
                uint2 kk;
                kk.x = pack2(k4[0], k4[1]);
                kk.y = pack2(k4[2], k4[3]);
                *reinterpret_cast<uint2*>(&Ksh[nxt][kstoff[rr]]) = kk;
            }
            f32x4 v4[4];
            #pragma unroll
            for (int i = 0; i < 4; ++i)
                v4[i] = *reinterpret_cast<const f32x4*>(
                    vh + (tb + rK * 4 + i) * DIMH + c4);
            #pragma unroll
            for (int j = 0; j < 4; ++j) {
                uint2 w;
                w.x = pack2(v4[0][j], v4[1][j]);
                w.y = pack2(v4[2][j], v4[3][j]);
                *reinterpret_cast<uint2*>(&Vt[nxt][vstoff[j]]) = w;
            }
        }

        __builtin_amdgcn_s_setprio(1);

        // ---- S^T = K (Q*QS)^T fused with exp2, per n-pair -> pa (u window: 16 regs) ----
        bf16x8 pa[4][2];
        #pragma unroll
        for (int np = 0; np < 2; ++np) {
            unsigned u[4][4];
            #pragma unroll
            for (int nn = 0; nn < 2; ++nn) {
                const int n = np * 2 + nn;
                bf16x8 kf0 = *reinterpret_cast<const bf16x8*>(&Kb[koff[n][0]]);
                bf16x8 kf1 = *reinterpret_cast<const bf16x8*>(&Kb[koff[n][1]]);
                #pragma unroll
                for (int h = 0; h < 4; ++h) {
                    f32x4 a = {0.f, 0.f, 0.f, 0.f};
                    a = __builtin_amdgcn_mfma_f32_16x16x32_bf16(kf0, qf[h][0], a, 0, 0, 0);
                    a = __builtin_amdgcn_mfma_f32_16x16x32_bf16(kf1, qf[h][1], a, 0, 0, 0);
                    u[h][2 * nn]     = pack2(EXP2(a[0]), EXP2(a[1]));
                    u[h][2 * nn + 1] = pack2(EXP2(a[2]), EXP2(a[3]));
                }
            }
            // T12 exchange: D-layout -> A-frag for this kv-32 half
            #pragma unroll
            for (int h = 0; h < 4; ++h) {
                unsigned a0 = u[h][0], b0 = u[h][2];
                unsigned a1 = u[h][1], b1 = u[h][3];
                perm32swap(a0, b0); perm16swap(a0, b0);
                perm32swap(a1, b1); perm16swap(a1, b1);
                union { unsigned w[4]; bf16x8 v; } pu;
                pu.w[0] = a0; pu.w[1] = a1; pu.w[2] = b0; pu.w[3] = b1;
                pa[h][np] = pu.v;
            }
        }

        // ---- row sums via MFMA against ones ----
        #pragma unroll
        for (int h = 0; h < 4; ++h) {
            lacc[h] = __builtin_amdgcn_mfma_f32_16x16x32_bf16(pa[h][0], ones, lacc[h], 0, 0, 0);
            lacc[h] = __builtin_amdgcn_mfma_f32_16x16x32_bf16(pa[h][1], ones, lacc[h], 0, 0, 0);
        }

        // ---- O += P V : V fragments read once, used by all four h ----
        #pragma unroll
        for (int d = 0; d < 4; ++d) {
            bf16x8 vb0 = *reinterpret_cast<const bf16x8*>(&Vb[koff[d][0]]);
            bf16x8 vb1 = *reinterpret_cast<const bf16x8*>(&Vb[koff[d][1]]);
            #pragma unroll
            for (int h = 0; h < 4; ++h) {
                oacc[h][d] = __builtin_amdgcn_mfma_f32_16x16x32_bf16(pa[h][0], vb0, oacc[h][d], 0, 0, 0);
                oacc[h][d] = __builtin_amdgcn_mfma_f32_16x16x32_bf16(pa[h][1], vb1, oacc[h][d], 0, 0, 0);
            }
        }

        __builtin_amdgcn_s_setprio(0);

        // ---- single end-of-iter barrier ----
        if (pf) {
            asm volatile("s_waitcnt lgkmcnt(0)" ::: "memory");
            __builtin_amdgcn_s_barrier();
            asm volatile("" ::: "memory");
        }
    }

    // ---- epilogue: normalize by row sum, store fp32 ----
    #pragma unroll
    for (int h = 0; h < 4; ++h)
        #pragma unroll
        for (int r = 0; r < 4; ++r) {
            float inv = 1.0f / lacc[h][r];
            float* dst = oh + (size_t)(q0 + h * 16 + lg * 4 + r) * DIMH;
            #pragma unroll
            for (int d = 0; d < 4; ++d)
                dst[d * 16 + l15] = oacc[h][d][r] * inv;
        }
}

extern "C" void kernel_launch(void* const* d_in, const int* in_sizes, int n_in,
                              void* d_out, int out_size, void* d_ws, size_t ws_size,
                              hipStream_t stream) {
    const float* q = (const float*)d_in[0];
    const float* k = (const float*)d_in[1];
    const float* v = (const float*)d_in[2];
    float* out = (float*)d_out;
    dim3 grid(64 * (SEQ / 256));   // 64 heads x 8 q-tiles = 512 blocks
    dim3 block(256);
    fattn<<<grid, block, 0, stream>>>(q, k, v, out);
}